// Round 9
// baseline (63.039 us; speedup 1.0000x reference)
//
#include <hip/hip_runtime.h>

// MeanTopKPooling2D: x [16,112,112,128] f32 -> out [16,110,110,128] f32
// out[pos,c] = mean(top4 over q of x[b, pix(q,base), c]), pos = b*12100+base.
// Key factorization: base = 9u+v; w = v+4q; t = q*1344 + w/9 + u; p = w%9;
//   pix = t + 2*(t/110) + 112*(p/3) + p%3
//       = K(v,q) + u + 2*(u/110) + 2*((C3(v,q) + u%110 >= 110) + (... >= 220))
//   with K, C3 compile-time per (v,q)  [verified: (0,0,0)->0, (0,0,1)->1481,
//   (1343,8,8)->12430 all match reference P-decode].
// Each (v,q) load feeds EXACTLY ONE output v -> 9 independent streams per
// wave. One wave = one u-group x 128 channels (f32x2/lane = full pixel/load).
// 3-deep rotating pipeline (gA/gB/gC) + sched_barrier fences = 18-27 loads
// in flight; addresses wave-uniform SALU; selection = med3-based sort4 (28
// ops/elem). R4-R8 showed single-merge-chain dataflow lets the scheduler
// collapse MLP to ~4 loads; independent streams are the fix.

typedef float f32x2 __attribute__((ext_vector_type(2)));

#define NPOS  12100u
#define NU    1345u              // u-groups per image (last one partial: v<=3)
#define NWG   5380               // (1345*16 waves)/4 per block
#define IMG_BYTES  (12544u*512u)
#define OUT_BYTES  (12100u*512u)

template<int V>
__device__ __forceinline__ void load_group(const char* __restrict__ imgb,
                                           unsigned base2, unsigned ul,
                                           unsigned vlane, f32x2 (&g)[9]) {
#pragma unroll
    for (int q = 0; q < 9; ++q) {
        const unsigned w    = (unsigned)(V + 4 * q);
        const unsigned C1   = w / 9u;
        const unsigned p    = w % 9u;
        const unsigned POFF = 112u * (p / 3u) + (p % 3u);
        const unsigned K    = (unsigned)q * 1344u + C1 + 24u * (unsigned)q + POFF;
        const unsigned C3   = 24u * (unsigned)q + C1;           // <= 196
        unsigned s3  = C3 + ul;                                 // <= 305
        unsigned e   = (s3 >= 110u ? 1u : 0u) + (s3 >= 220u ? 1u : 0u);
        unsigned pix = K + base2 + 2u * e;
        pix = pix > 12543u ? 12543u : pix;   // only bites at u=1344 tail
        g[q] = *reinterpret_cast<const f32x2*>(imgb + pix * 512u + vlane);
    }
}

template<int V>
__device__ __forceinline__ void sel_store(const f32x2 (&g)[9],
                                          char* __restrict__ outb,
                                          unsigned u, unsigned vlane) {
    unsigned pos = 9u * u + (unsigned)V;
    float r[2];
#pragma unroll
    for (int e = 0; e < 2; ++e) {
        float a0 = g[0][e], a1 = g[1][e], a2 = g[2][e], a3 = g[3][e];
        float b0 = g[4][e], b1 = g[5][e], b2 = g[6][e], b3 = g[7][e];
        float v8 = g[8][e];
        // sort4 desc via sort3(max3/min3/med3) + med3 insertion: 7 ops
        float xa = fmaxf(fmaxf(a0, a1), a2);
        float za = fminf(fminf(a0, a1), a2);
        float ya = __builtin_amdgcn_fmed3f(a0, a1, a2);
        float s0 = fmaxf(xa, a3);
        float s1 = __builtin_amdgcn_fmed3f(xa, a3, ya);
        float s2 = __builtin_amdgcn_fmed3f(ya, a3, za);
        float s3 = fminf(za, a3);
        float xb = fmaxf(fmaxf(b0, b1), b2);
        float zb = fminf(fminf(b0, b1), b2);
        float yb = __builtin_amdgcn_fmed3f(b0, b1, b2);
        float t0 = fmaxf(xb, b3);
        float t1 = __builtin_amdgcn_fmed3f(xb, b3, yb);
        float t2 = __builtin_amdgcn_fmed3f(yb, b3, zb);
        float t3 = fminf(zb, b3);
        // bitonic half-cleaner: top-4 multiset of 8
        float m0 = fmaxf(s0, t3);
        float m1 = fmaxf(s1, t2);
        float m2 = fmaxf(s2, t1);
        float m3 = fmaxf(s3, t0);
        // top4 of {m0..m3, v8} = sum5 - min5
        float sum = (m0 + m1) + (m2 + m3) + v8;
        float mn  = fminf(fminf(fminf(m0, m1), fminf(m2, m3)), v8);
        r[e] = (sum - mn) * 0.25f;
    }
    if (pos < NPOS) {
        f32x2 rv = {r[0], r[1]};
        __builtin_nontemporal_store(
            rv, reinterpret_cast<f32x2*>(outb + pos * 512u + vlane));
    }
}

#define SB() __builtin_amdgcn_sched_barrier(0)

__global__ __launch_bounds__(256) void meantopk_kernel(const float* __restrict__ x,
                                                       float* __restrict__ out) {
    // bijective XCD swizzle, NWG = 5380 = 8*672 + 4
    unsigned bid = blockIdx.x;
    unsigned xcd = bid & 7u, idx = bid >> 3;
    unsigned wg  = (xcd < 4u ? xcd * 673u : 4u * 673u + (xcd - 4u) * 672u) + idx;

    unsigned lane = threadIdx.x & 63u;
    unsigned wid  = threadIdx.x >> 6;
    unsigned W    = wg * 4u + wid;
    unsigned u    = (unsigned)__builtin_amdgcn_readfirstlane(W % NU);
    unsigned b    = (unsigned)__builtin_amdgcn_readfirstlane(W / NU);

    unsigned uh    = u / 110u;
    unsigned ul    = u - uh * 110u;
    unsigned base2 = u + 2u * uh;

    const char* imgb = reinterpret_cast<const char*>(x) + (size_t)b * IMG_BYTES;
    char*       outb = reinterpret_cast<char*>(out)     + (size_t)b * OUT_BYTES;
    unsigned vlane = lane * 8u;          // byte offset of this lane's f32x2

    f32x2 gA[9], gB[9], gC[9];
    load_group<0>(imgb, base2, ul, vlane, gA);
    load_group<1>(imgb, base2, ul, vlane, gB);
    SB();
    load_group<2>(imgb, base2, ul, vlane, gC);
    SB();
    sel_store<0>(gA, outb, u, vlane); SB();
    load_group<3>(imgb, base2, ul, vlane, gA); SB();
    sel_store<1>(gB, outb, u, vlane); SB();
    load_group<4>(imgb, base2, ul, vlane, gB); SB();
    sel_store<2>(gC, outb, u, vlane); SB();
    load_group<5>(imgb, base2, ul, vlane, gC); SB();
    sel_store<3>(gA, outb, u, vlane); SB();
    load_group<6>(imgb, base2, ul, vlane, gA); SB();
    sel_store<4>(gB, outb, u, vlane); SB();
    load_group<7>(imgb, base2, ul, vlane, gB); SB();
    sel_store<5>(gC, outb, u, vlane); SB();
    load_group<8>(imgb, base2, ul, vlane, gC); SB();
    sel_store<6>(gA, outb, u, vlane); SB();
    sel_store<7>(gB, outb, u, vlane); SB();
    sel_store<8>(gC, outb, u, vlane);
}

extern "C" void kernel_launch(void* const* d_in, const int* in_sizes, int n_in,
                              void* d_out, int out_size, void* d_ws, size_t ws_size,
                              hipStream_t stream) {
    const float* x = (const float*)d_in[0];
    float* out = (float*)d_out;
    meantopk_kernel<<<NWG, 256, 0, stream>>>(x, out);
}

// Round 10
// 45.471 us; speedup vs baseline: 1.3863x; 1.3863x over previous
//
#include <hip/hip_runtime.h>

// MeanTopKPooling2D: x [16,112,112,128] f32 -> out [16,110,110,128] f32
// out[pos,c] = mean(top4 over q of x[b, pix(q,base), c]); pos = b*12100+base;
//   w=v+4q (base=9u+v); t=q*1344+u+w/9; p=w%9; pix=t+2*(t/110)+112*(p/3)+p%3
//
// R10: L1-line-utilization layout. Thread owns 16B slot c16=tid&7 of its pos;
// 8 lanes x 16B = one fully-consumed 128B line per pos per load instruction
// (R4's 32B-strided lanes touched every line twice at 50% use -> 2x the L1
// tag lookups; 13.9M lookups ~ the 51us wall). Thread covers 16 channels via
// 4 dwordx4 at c16*16 + j*128; address chain computed once per thread
// (amortized 2x vs R4). Two register-reusing halves keep VGPR moderate.

typedef float f32x4 __attribute__((ext_vector_type(4)));

#define NPOS 12100u
#define NWG  6050            // 193600 pos * 8 thr / 256
#define IMG_BYTES (12544u * 512u)

__global__ __launch_bounds__(256) void meantopk_kernel(const float* __restrict__ x,
                                                       float* __restrict__ out) {
    // bijective XCD swizzle: 6050 = 8*756 + 2
    unsigned bid = blockIdx.x;
    unsigned xcd = bid & 7u, idx = bid >> 3;
    unsigned wg  = (xcd < 2u ? xcd * 757u : 2u * 757u + (xcd - 2u) * 756u) + idx;

    unsigned tid = wg * 256u + threadIdx.x;
    unsigned c16 = tid & 7u;             // 16B slot within the 512B pixel
    unsigned pos = tid >> 3;             // b*12100 + base
    unsigned base = pos % NPOS;
    unsigned b    = pos / NPOS;
    unsigned u = base / 9u;
    unsigned v = base % 9u;

    // 9 pixel byte-offsets, computed once (amortized over 16 channels)
    unsigned off[9];
#pragma unroll
    for (int q = 0; q < 9; ++q) {
        unsigned w = v + 4u * (unsigned)q;
        unsigned t = (unsigned)q * 1344u + u + w / 9u;
        unsigned p = w % 9u;
        unsigned pix = t + 2u * (t / 110u) + 112u * (p / 3u) + (p % 3u);
        off[q] = pix * 512u;
    }

    const char* xb = reinterpret_cast<const char*>(x) + (size_t)b * IMG_BYTES + c16 * 16u;
    char*       ob = reinterpret_cast<char*>(out) + (size_t)pos * 512u + c16 * 16u;

#pragma unroll
    for (int h = 0; h < 2; ++h) {        // half h covers j = 2h, 2h+1 (8 channels)
        f32x4 va[9][2];
#pragma unroll
        for (int q = 0; q < 9; ++q) {
            const char* a = xb + off[q] + (unsigned)h * 256u;
            va[q][0] = *reinterpret_cast<const f32x4*>(a);          // j = 2h
            va[q][1] = *reinterpret_cast<const f32x4*>(a + 128u);   // j = 2h+1
        }
        // keep the 18-load cluster issued before any consumer
        __builtin_amdgcn_sched_barrier(0);

        f32x4 r[2];
#pragma unroll
        for (int j = 0; j < 2; ++j) {
#pragma unroll
            for (int e = 0; e < 4; ++e) {
                float a0 = va[0][j][e], a1 = va[1][j][e], a2 = va[2][j][e], a3 = va[3][j][e];
                float b0 = va[4][j][e], b1 = va[5][j][e], b2 = va[6][j][e], b3 = va[7][j][e];
                float v8 = va[8][j][e];
                // sort4 desc via sort3(max/min/med3) + med3 insertion (9 ops)
                float xa = fmaxf(fmaxf(a0, a1), a2);
                float za = fminf(fminf(a0, a1), a2);
                float ya = __builtin_amdgcn_fmed3f(a0, a1, a2);
                float s0 = fmaxf(xa, a3);
                float s1 = __builtin_amdgcn_fmed3f(xa, a3, ya);
                float s2 = __builtin_amdgcn_fmed3f(ya, a3, za);
                float s3 = fminf(za, a3);
                float xb2 = fmaxf(fmaxf(b0, b1), b2);
                float zb = fminf(fminf(b0, b1), b2);
                float yb = __builtin_amdgcn_fmed3f(b0, b1, b2);
                float t0 = fmaxf(xb2, b3);
                float t1 = __builtin_amdgcn_fmed3f(xb2, b3, yb);
                float t2 = __builtin_amdgcn_fmed3f(yb, b3, zb);
                float t3 = fminf(zb, b3);
                // bitonic half-cleaner: top-4 multiset of 8
                float m0 = fmaxf(s0, t3);
                float m1 = fmaxf(s1, t2);
                float m2 = fmaxf(s2, t1);
                float m3 = fmaxf(s3, t0);
                // top4 of {m0..m3, v8} = sum5 - min5
                float sum = (m0 + m1) + (m2 + m3) + v8;
                float mn  = fminf(fminf(fminf(m0, m1), fminf(m2, m3)), v8);
                r[j][e] = (sum - mn) * 0.25f;
            }
        }
        __builtin_nontemporal_store(r[0], reinterpret_cast<f32x4*>(ob + (unsigned)h * 256u));
        __builtin_nontemporal_store(r[1], reinterpret_cast<f32x4*>(ob + (unsigned)h * 256u + 128u));
    }
}

extern "C" void kernel_launch(void* const* d_in, const int* in_sizes, int n_in,
                              void* d_out, int out_size, void* d_ws, size_t ws_size,
                              hipStream_t stream) {
    const float* x = (const float*)d_in[0];
    float* out = (float*)d_out;
    meantopk_kernel<<<NWG, 256, 0, stream>>>(x, out);
}

// Round 11
// 44.488 us; speedup vs baseline: 1.4170x; 1.0221x over previous
//
#include <hip/hip_runtime.h>

// MeanTopKPooling2D: x [16,112,112,128] f32 -> out [16,110,110,128] f32
// out[pos,c] = mean(top4 over q of x[b, pix(q,base), c]); pos = b*12100+base;
//   w=v+4q (base=9u+v); t=q*1344+u+w/9; p=w%9; pix=t+2*(t/110)+112*(p/3)+p%3
//
// R11 = R10's full-line layout (thread owns 16B slot c16 of a 128B line; 8
// lanes x 16B = one fully-consumed line per pos per load) with the two
// channel-halves split into separate threads: thread = (pos, c16, h), 8
// channels, 18 loads -> 48,400 waves (2x R10's TLP; R10 showed 28% occupancy
// and intra-thread half-serialization as the residual latency gap).

typedef float f32x4 __attribute__((ext_vector_type(4)));

#define NPOS 12100u
#define NWG  12100           // 193600 pos * 16 thr / 256
#define IMG_BYTES (12544u * 512u)

__global__ __launch_bounds__(256) void meantopk_kernel(const float* __restrict__ x,
                                                       float* __restrict__ out) {
    // bijective XCD swizzle: 12100 = 8*1512 + 4
    const unsigned NX = 8u;
    unsigned bid = blockIdx.x;
    const unsigned qq = NWG / NX;        // 1512
    const unsigned rr = NWG % NX;        // 4
    unsigned xcd = bid % NX;
    unsigned idx = bid / NX;
    unsigned wg = (xcd < rr ? xcd * (qq + 1u)
                            : rr * (qq + 1u) + (xcd - rr) * qq) + idx;

    unsigned tid = wg * 256u + threadIdx.x;
    unsigned c16 = tid & 7u;             // 16B slot within a 128B line
    unsigned h   = (tid >> 3) & 1u;      // which pair of lines (channels 0-63 / 64-127)
    unsigned pos = tid >> 4;             // b*12100 + base
    unsigned base = pos % NPOS;
    unsigned b    = pos / NPOS;
    unsigned u = base / 9u;
    unsigned v = base % 9u;

    // 9 pixel byte-offsets (amortized over 8 channels)
    unsigned off[9];
#pragma unroll
    for (int q = 0; q < 9; ++q) {
        unsigned w = v + 4u * (unsigned)q;
        unsigned t = (unsigned)q * 1344u + u + w / 9u;
        unsigned p = w % 9u;
        unsigned pix = t + 2u * (t / 110u) + 112u * (p / 3u) + (p % 3u);
        off[q] = pix * 512u;
    }

    unsigned slot = c16 * 16u + h * 256u;    // byte offset within the 512B pixel
    const char* xb = reinterpret_cast<const char*>(x) + (size_t)b * IMG_BYTES + slot;
    char*       ob = reinterpret_cast<char*>(out) + (size_t)pos * 512u + slot;

    f32x4 va[9][2];
#pragma unroll
    for (int q = 0; q < 9; ++q) {
        const char* a = xb + off[q];
        va[q][0] = *reinterpret_cast<const f32x4*>(a);          // line 2h
        va[q][1] = *reinterpret_cast<const f32x4*>(a + 128u);   // line 2h+1
    }
    // keep the 18-load cluster issued before any consumer
    __builtin_amdgcn_sched_barrier(0);

    f32x4 r[2];
#pragma unroll
    for (int j = 0; j < 2; ++j) {
#pragma unroll
        for (int e = 0; e < 4; ++e) {
            float a0 = va[0][j][e], a1 = va[1][j][e], a2 = va[2][j][e], a3 = va[3][j][e];
            float b0 = va[4][j][e], b1 = va[5][j][e], b2 = va[6][j][e], b3 = va[7][j][e];
            float v8 = va[8][j][e];
            // sort4 desc via sort3(max/min/med3) + med3 insertion
            float xa = fmaxf(fmaxf(a0, a1), a2);
            float za = fminf(fminf(a0, a1), a2);
            float ya = __builtin_amdgcn_fmed3f(a0, a1, a2);
            float s0 = fmaxf(xa, a3);
            float s1 = __builtin_amdgcn_fmed3f(xa, a3, ya);
            float s2 = __builtin_amdgcn_fmed3f(ya, a3, za);
            float s3 = fminf(za, a3);
            float xb2 = fmaxf(fmaxf(b0, b1), b2);
            float zb = fminf(fminf(b0, b1), b2);
            float yb = __builtin_amdgcn_fmed3f(b0, b1, b2);
            float t0 = fmaxf(xb2, b3);
            float t1 = __builtin_amdgcn_fmed3f(xb2, b3, yb);
            float t2 = __builtin_amdgcn_fmed3f(yb, b3, zb);
            float t3 = fminf(zb, b3);
            // bitonic half-cleaner: top-4 multiset of 8
            float m0 = fmaxf(s0, t3);
            float m1 = fmaxf(s1, t2);
            float m2 = fmaxf(s2, t1);
            float m3 = fmaxf(s3, t0);
            // top4 of {m0..m3, v8} = sum5 - min5
            float sum = (m0 + m1) + (m2 + m3) + v8;
            float mn  = fminf(fminf(fminf(m0, m1), fminf(m2, m3)), v8);
            r[j][e] = (sum - mn) * 0.25f;
        }
    }
    __builtin_nontemporal_store(r[0], reinterpret_cast<f32x4*>(ob));
    __builtin_nontemporal_store(r[1], reinterpret_cast<f32x4*>(ob + 128u));
}

extern "C" void kernel_launch(void* const* d_in, const int* in_sizes, int n_in,
                              void* d_out, int out_size, void* d_ws, size_t ws_size,
                              hipStream_t stream) {
    const float* x = (const float*)d_in[0];
    float* out = (float*)d_out;
    meantopk_kernel<<<NWG, 256, 0, stream>>>(x, out);
}

// Round 12
// 43.355 us; speedup vs baseline: 1.4540x; 1.0261x over previous
//
#include <hip/hip_runtime.h>

// MeanTopKPooling2D: x [16,112,112,128] f32 -> out [16,110,110,128] f32
// out[pos,c] = mean(top4 over q of x[b, pix(q,base), c]); pos = b*12100+base;
//   w=v+4q (base=9u+v); t=q*1344+u+w/9; p=w%9; pix=t+2*(t/110)+112*(p/3)+p%3
//
// R12 = R11's full-line layout (thread = (pos, c16, h): 16B slot of a 128B
// line, 8 lanes x 16B = one fully-consumed line per load; 18 loads/thread)
// + LDS ADDRESS PRECOMPUTE: block covers 16 pos; threads 0-143 compute one
// (pos,q) byte-offset each (incl. b*IMG term) into lds_off[16][9]; phase 2 is
// division-free (9 broadcast ds_read_b32, conflict-free: 4 distinct banks).
// R11 showed effective VALUBusy ~66% with the 9-chain magic-div address math
// replicated 16x per pos (~180 VALU/thread) - that redundancy is the target.

typedef float f32x4 __attribute__((ext_vector_type(4)));

#define NPOS 12100u
#define NWG  12100           // 193600 pos * 16 thr / 256
#define IMG_BYTES (12544u * 512u)

__global__ __launch_bounds__(256) void meantopk_kernel(const float* __restrict__ x,
                                                       float* __restrict__ out) {
    __shared__ unsigned lds_off[16][9];

    // bijective XCD swizzle: 12100 = 8*1512 + 4
    const unsigned NX = 8u;
    unsigned bid = blockIdx.x;
    const unsigned qq = NWG / NX;        // 1512
    const unsigned rr = NWG % NX;        // 4
    unsigned xcd = bid % NX;
    unsigned idx = bid / NX;
    unsigned wg = (xcd < rr ? xcd * (qq + 1u)
                            : rr * (qq + 1u) + (xcd - rr) * qq) + idx;

    // ---- phase 1: 144 threads compute one (pos-local, q) offset each ----
    unsigned tx = threadIdx.x;
    if (tx < 144u) {
        unsigned lp = tx / 9u;
        unsigned q  = tx - lp * 9u;
        unsigned pos = wg * 16u + lp;
        unsigned base = pos % NPOS;
        unsigned b    = pos / NPOS;
        unsigned u = base / 9u;
        unsigned v = base - u * 9u;
        unsigned w = v + 4u * q;
        unsigned c1 = w / 9u;
        unsigned t  = q * 1344u + u + c1;
        unsigned p  = w - c1 * 9u;
        unsigned p3 = p / 3u;
        unsigned pix = t + 2u * (t / 110u) + 112u * p3 + (p - p3 * 3u);
        lds_off[lp][q] = b * IMG_BYTES + pix * 512u;
    }
    __syncthreads();

    // ---- phase 2: division-free ----
    unsigned tid = wg * 256u + tx;
    unsigned c16 = tid & 7u;             // 16B slot within a 128B line
    unsigned h   = (tid >> 3) & 1u;      // line pair (channels 0-63 / 64-127)
    unsigned lp  = tx >> 4;              // pos-local within block
    unsigned pos = tid >> 4;

    unsigned off[9];
#pragma unroll
    for (int q = 0; q < 9; ++q) off[q] = lds_off[lp][q];

    unsigned slot = c16 * 16u + h * 256u;
    const char* xb = reinterpret_cast<const char*>(x) + slot;
    char*       ob = reinterpret_cast<char*>(out) + (size_t)pos * 512u + slot;

    f32x4 va[9][2];
#pragma unroll
    for (int q = 0; q < 9; ++q) {
        const char* a = xb + off[q];
        va[q][0] = *reinterpret_cast<const f32x4*>(a);          // line 2h
        va[q][1] = *reinterpret_cast<const f32x4*>(a + 128u);   // line 2h+1
    }
    // keep the 18-load cluster issued before any consumer
    __builtin_amdgcn_sched_barrier(0);

    f32x4 r[2];
#pragma unroll
    for (int j = 0; j < 2; ++j) {
#pragma unroll
        for (int e = 0; e < 4; ++e) {
            float a0 = va[0][j][e], a1 = va[1][j][e], a2 = va[2][j][e], a3 = va[3][j][e];
            float b0 = va[4][j][e], b1 = va[5][j][e], b2 = va[6][j][e], b3 = va[7][j][e];
            float v8 = va[8][j][e];
            // sort4 desc via sort3(max3/min3/med3) + med3 insertion
            float xa = fmaxf(fmaxf(a0, a1), a2);
            float za = fminf(fminf(a0, a1), a2);
            float ya = __builtin_amdgcn_fmed3f(a0, a1, a2);
            float s0 = fmaxf(xa, a3);
            float s1 = __builtin_amdgcn_fmed3f(xa, a3, ya);
            float s2 = __builtin_amdgcn_fmed3f(ya, a3, za);
            float s3 = fminf(za, a3);
            float xb2 = fmaxf(fmaxf(b0, b1), b2);
            float zb = fminf(fminf(b0, b1), b2);
            float yb = __builtin_amdgcn_fmed3f(b0, b1, b2);
            float t0 = fmaxf(xb2, b3);
            float t1 = __builtin_amdgcn_fmed3f(xb2, b3, yb);
            float t2 = __builtin_amdgcn_fmed3f(yb, b3, zb);
            float t3 = fminf(zb, b3);
            // bitonic half-cleaner: top-4 multiset of 8
            float m0 = fmaxf(s0, t3);
            float m1 = fmaxf(s1, t2);
            float m2 = fmaxf(s2, t1);
            float m3 = fmaxf(s3, t0);
            // top4 of {m0..m3, v8} = sum5 - min5
            float sum = (m0 + m1) + (m2 + m3) + v8;
            float mn  = fminf(fminf(fminf(m0, m1), fminf(m2, m3)), v8);
            r[j][e] = (sum - mn) * 0.25f;
        }
    }
    __builtin_nontemporal_store(r[0], reinterpret_cast<f32x4*>(ob));
    __builtin_nontemporal_store(r[1], reinterpret_cast<f32x4*>(ob + 128u));
}

extern "C" void kernel_launch(void* const* d_in, const int* in_sizes, int n_in,
                              void* d_out, int out_size, void* d_ws, size_t ws_size,
                              hipStream_t stream) {
    const float* x = (const float*)d_in[0];
    float* out = (float*)d_out;
    meantopk_kernel<<<NWG, 256, 0, stream>>>(x, out);
}